// Round 2
// baseline (2684.113 us; speedup 1.0000x reference)
//
#include <hip/hip_runtime.h>
#include <cstdint>

#define B_ 16
#define C_ 16
#define H_ 128
#define W_ 128
#define HID_ 128
#define NSTEPS 24
#define THR 0.1f
#define TSX 32
#define TSY 16
#define TPX 34
#define TPY 18
#define FRAMES 25
#define CHW (C_*H_*W_)
#define HW (H_*W_)

typedef float v2f __attribute__((ext_vector_type(2)));

#define VFMA(a,b,c) __builtin_elementwise_fma((a),(b),(c))

// k-index (0..47) -> element of v2f D[24]
#define SETD(D,k,v) do { if ((k)&1) (D)[(k)>>1].y = (v); else (D)[(k)>>1].x = (v); } while(0)
#define GETD(D,k) (((k)&1) ? (D)[(k)>>1].y : (D)[(k)>>1].x)

// frame 0 = input x, copied batch-wise into the strided output layout
__global__ void frame0_copy(const float4* __restrict__ x, float4* __restrict__ out) {
    int idx = blockIdx.x * 256 + threadIdx.x;      // over B*C*H*W/4 = 1,048,576
    int per_b = CHW / 4;
    int b = idx / per_b;
    int r = idx - b * per_b;
    out[(size_t)b * (FRAMES * CHW / 4) + r] = x[idx];
}

// w2 (C, HID) -> w2t (HID, C) so the h-loop reads 16 contiguous dwords
__global__ void w2_transpose(const float* __restrict__ w2, float* __restrict__ w2t) {
    int i = blockIdx.x * 256 + threadIdx.x;        // 2048
    int c = i >> 7, h = i & 127;
    w2t[h * C_ + c] = w2[i];
}

// stepA: read frame s, LDS tile 16x32 + 1-halo (wrap), pre-life, depthwise conv,
// MLP 48->128->16 for TWO pixels per thread (x and x+16), packed-f32 dot products.
// Writes UNMASKED x+delta to x1 and pre-life to premask.
__global__ __launch_bounds__(256) void stepA(
    const float* __restrict__ frames,   // d_out base
    const float* __restrict__ w1,       // (128,48) row-major
    const float* __restrict__ b1,       // (128)
    const float* __restrict__ w2t,      // (128,16)
    float* __restrict__ x1,
    float* __restrict__ premask,
    int s)
{
    __shared__ float xs[C_][TPY][TPX];
    const int b = blockIdx.z;
    const int ty0 = blockIdx.y * TSY, tx0 = blockIdx.x * TSX;
    const int tid = threadIdx.x;
    const float* xin = frames + ((size_t)b * FRAMES + s) * CHW;

    // cooperative halo load with wrap (18x34 positions, 16 channels each)
    for (int p = tid; p < TPY * TPX; p += 256) {
        int iy = p / TPX, ix = p - iy * TPX;
        int gy = (ty0 + iy - 1) & (H_ - 1);
        int gx = (tx0 + ix - 1) & (W_ - 1);
        const float* src = xin + gy * W_ + gx;
        #pragma unroll
        for (int c = 0; c < C_; ++c)
            xs[c][iy][ix] = src[c * HW];
    }
    __syncthreads();

    const int ly = tid >> 4, lx = tid & 15;
    // pixel0 at (ly, lx), pixel1 at (ly, lx+16)

    // pre_life: 3x3 max over channel 0 of padded x, both pixels
    float m0 = -1e30f, m1 = -1e30f;
    #pragma unroll
    for (int dy = 0; dy < 3; ++dy)
        #pragma unroll
        for (int dx = 0; dx < 3; ++dx) {
            m0 = fmaxf(m0, xs[0][ly + dy][lx + dx]);
            m1 = fmaxf(m1, xs[0][ly + dy][lx + 16 + dx]);
        }
    const float pre0 = (m0 > THR) ? 1.0f : 0.0f;
    const float pre1 = (m1 > THR) ? 1.0f : 0.0f;

    // depthwise conv -> D[24] v2f per pixel (interleaved [id, sobel_x, sobel_y])
    v2f D0[24], D1[24];
    #pragma unroll
    for (int c = 0; c < C_; ++c) {
        {
            float a00 = xs[c][ly][lx],     a01 = xs[c][ly][lx + 1],     a02 = xs[c][ly][lx + 2];
            float a10 = xs[c][ly + 1][lx],                              a12 = xs[c][ly + 1][lx + 2];
            float a20 = xs[c][ly + 2][lx], a21 = xs[c][ly + 2][lx + 1], a22 = xs[c][ly + 2][lx + 2];
            float a11 = xs[c][ly + 1][lx + 1];
            SETD(D0, 3 * c,     a11);
            SETD(D0, 3 * c + 1, (a02 - a00 + 2.0f * (a12 - a10) + a22 - a20) * 0.125f);
            SETD(D0, 3 * c + 2, (a00 + 2.0f * a01 + a02 - a20 - 2.0f * a21 - a22) * 0.125f);
        }
        {
            int kx = lx + 16;
            float a00 = xs[c][ly][kx],     a01 = xs[c][ly][kx + 1],     a02 = xs[c][ly][kx + 2];
            float a10 = xs[c][ly + 1][kx],                              a12 = xs[c][ly + 1][kx + 2];
            float a20 = xs[c][ly + 2][kx], a21 = xs[c][ly + 2][kx + 1], a22 = xs[c][ly + 2][kx + 2];
            float a11 = xs[c][ly + 1][kx + 1];
            SETD(D1, 3 * c,     a11);
            SETD(D1, 3 * c + 1, (a02 - a00 + 2.0f * (a12 - a10) + a22 - a20) * 0.125f);
            SETD(D1, 3 * c + 2, (a00 + 2.0f * a01 + a02 - a20 - 2.0f * a21 - a22) * 0.125f);
        }
    }

    const v2f* __restrict__ w1v = (const v2f*)w1;    // row h: w1v[h*24 + j]
    const v2f* __restrict__ w2v = (const v2f*)w2t;   // row h: w2v[h*8 + j], (c2j, c2j+1)

    v2f A0[8], A1[8];                                // delta accumulators, c-pairs
    #pragma unroll
    for (int j = 0; j < 8; ++j) {
        A0[j].x = 0.0f; A0[j].y = 0.0f;
        A1[j].x = 0.0f; A1[j].y = 0.0f;
    }

    for (int h = 0; h < HID_; ++h) {
        const v2f* wr = w1v + h * 24;
        v2f s0a, s0b, s1a, s1b;
        s0a.x = 0.f; s0a.y = 0.f; s0b.x = 0.f; s0b.y = 0.f;
        s1a.x = 0.f; s1a.y = 0.f; s1b.x = 0.f; s1b.y = 0.f;
        #pragma unroll
        for (int j = 0; j < 24; j += 2) {
            v2f wa = wr[j], wb = wr[j + 1];
            s0a = VFMA(wa, D0[j],     s0a);
            s0b = VFMA(wb, D0[j + 1], s0b);
            s1a = VFMA(wa, D1[j],     s1a);
            s1b = VFMA(wb, D1[j + 1], s1b);
        }
        float bb = b1[h];
        float hv0 = fmaxf((s0a.x + s0a.y) + (s0b.x + s0b.y) + bb, 0.0f);
        float hv1 = fmaxf((s1a.x + s1a.y) + (s1b.x + s1b.y) + bb, 0.0f);
        v2f hp0; hp0.x = hv0; hp0.y = hv0;
        v2f hp1; hp1.x = hv1; hp1.y = hv1;
        const v2f* wc = w2v + h * 8;
        #pragma unroll
        for (int j = 0; j < 8; ++j) {
            v2f wcj = wc[j];
            A0[j] = VFMA(wcj, hp0, A0[j]);
            A1[j] = VFMA(wcj, hp1, A1[j]);
        }
    }

    const int y = ty0 + ly;
    const int xcol = tx0 + lx;
    float* xo0 = x1 + (size_t)b * CHW + y * W_ + xcol;
    float* xo1 = xo0 + 16;
    #pragma unroll
    for (int c = 0; c < C_; ++c) {
        float dd0 = ((c) & 1) ? A0[c >> 1].y : A0[c >> 1].x;
        float dd1 = ((c) & 1) ? A1[c >> 1].y : A1[c >> 1].x;
        xo0[c * HW] = GETD(D0, 3 * c) + dd0;   // identity tap = old x
        xo1[c * HW] = GETD(D1, 3 * c) + dd1;
    }
    int pmi = b * HW + y * W_ + xcol;
    premask[pmi] = pre0;
    premask[pmi + 16] = pre1;
}

// stepB: post-life on unmasked x1 channel 0 (wrap), combine with pre-life,
// write masked state as frame s+1.
__global__ __launch_bounds__(256) void stepB(
    const float* __restrict__ x1,
    const float* __restrict__ premask,
    float* __restrict__ frames,
    int s)
{
    int idx = blockIdx.x * 256 + threadIdx.x;   // over B*H*W = 262144
    int b = idx >> 14;
    int yx = idx & (HW - 1);
    int y = yx >> 7, x = yx & (W_ - 1);
    const float* c0 = x1 + (size_t)b * CHW;
    float m = -1e30f;
    #pragma unroll
    for (int dy = -1; dy <= 1; ++dy) {
        int gy = (y + dy) & (H_ - 1);
        #pragma unroll
        for (int dx = -1; dx <= 1; ++dx) {
            int gx = (x + dx) & (W_ - 1);
            m = fmaxf(m, c0[gy * W_ + gx]);
        }
    }
    float life = (m > THR && premask[idx] != 0.0f) ? 1.0f : 0.0f;
    const float* xi = x1 + (size_t)b * CHW + yx;
    float* xo = frames + ((size_t)b * FRAMES + s + 1) * CHW + yx;
    #pragma unroll
    for (int c = 0; c < C_; ++c)
        xo[c * HW] = xi[c * HW] * life;
}

extern "C" void kernel_launch(void* const* d_in, const int* in_sizes, int n_in,
                              void* d_out, int out_size, void* d_ws, size_t ws_size,
                              hipStream_t stream)
{
    const float* x  = (const float*)d_in[0];
    const float* w1 = (const float*)d_in[1];
    const float* b1 = (const float*)d_in[2];
    const float* w2 = (const float*)d_in[3];
    // d_in[4] = steps (fixed at 24 for this problem)
    float* out = (float*)d_out;

    float* x1      = (float*)d_ws;                                        // 16 MB
    float* premask = (float*)((char*)d_ws + (size_t)B_ * CHW * 4);        // 1 MB
    float* w2t     = (float*)((char*)d_ws + (size_t)B_ * CHW * 4 + (size_t)B_ * HW * 4);

    w2_transpose<<<8, 256, 0, stream>>>(w2, w2t);
    frame0_copy<<<(B_ * CHW / 4) / 256, 256, 0, stream>>>((const float4*)x, (float4*)out);

    for (int s = 0; s < NSTEPS; ++s) {
        stepA<<<dim3(W_ / TSX, H_ / TSY, B_), 256, 0, stream>>>(out, w1, b1, w2t, x1, premask, s);
        stepB<<<(B_ * HW) / 256, 256, 0, stream>>>(x1, premask, out, s);
    }
}